// Round 13
// baseline (1980.675 us; speedup 1.0000x reference)
//
#include <hip/hip_runtime.h>

typedef unsigned short u16;
typedef __bf16 bf16x8 __attribute__((ext_vector_type(8)));
typedef float f32x4 __attribute__((ext_vector_type(4)));

#define T_TOK 200704   // 4*224*224
#define NTOK 49
#define SA 264         // stride (u16) for [49][256]/[64][256] LDS tiles
#define SP 72          // per-head Q/P row stride (144 B)
#define SH 136         // mlp hidden-chunk LDS stride (272 B rows)

__device__ __forceinline__ u16 f2bf(float f) {
    union { float f; unsigned u; } v; v.f = f;
    return (u16)((v.u + 0x7FFFu + ((v.u >> 16) & 1u)) >> 16);
}
__device__ __forceinline__ float bf2f(u16 b) {
    union { float f; unsigned u; } v; v.u = ((unsigned)b) << 16; return v.f;
}
__device__ __forceinline__ bf16x8 zfrag() {
    bf16x8 z;
#pragma unroll
    for (int i = 0; i < 8; ++i) z[i] = (__bf16)0.0f;
    return z;
}
__device__ __forceinline__ float gelu_f(float x) {
    float z = 0.7978845608f * (x + 0.044715f * x * x * x);
    float az = fabsf(z);
    float e = __expf(-2.0f * az);
    float t = (1.0f - e) / (1.0f + e);
    t = (z < 0.0f) ? -t : t;
    return 0.5f * x * (1.0f + t);
}

// ---------------- merged transpose: 10 matrices in one launch ----------------
struct TPack {
    const float* in[10];
    u16* out[10];
    int K[10], N[10];
};
__global__ void k_transpose_all(TPack p) {
    const int m = blockIdx.y;
    const int K = p.K[m], N = p.N[m];
    int idx = blockIdx.x * blockDim.x + threadIdx.x;
    if (idx >= K * N) return;
    int k = idx / N, n = idx - k * N;
    p.out[m][n * K + k] = f2bf(p.in[m][idx]);
}

// Full-height GEMM: out[49 x 64-strip] = A(49x256) @ W; A stride SA in LDS.
__device__ __forceinline__ void gemm49f(const u16* A, const u16* WT,
                                        int nb, int lane, f32x4 acc[4][4]) {
    const int ar = lane & 15;
    const int kg = (lane >> 4) * 8;
    const bf16x8 z = zfrag();
    for (int k0 = 0; k0 < 256; k0 += 32) {
        bf16x8 a[4], bb[4];
#pragma unroll
        for (int mt = 0; mt < 4; ++mt) {
            int row = mt * 16 + ar;
            a[mt] = (row < NTOK) ? *(const bf16x8*)(A + row * SA + k0 + kg) : z;
        }
#pragma unroll
        for (int nt = 0; nt < 4; ++nt) {
            int col = nb + nt * 16 + ar;
            bb[nt] = *(const bf16x8*)(WT + col * 256 + k0 + kg);
        }
#pragma unroll
        for (int mt = 0; mt < 4; ++mt)
#pragma unroll
            for (int nt = 0; nt < 4; ++nt)
                acc[mt][nt] = __builtin_amdgcn_mfma_f32_16x16x32_bf16(a[mt], bb[nt], acc[mt][nt], 0, 0, 0);
    }
}

// ---------------- dense KV projection: stage enc ONCE, 4 outputs ----------------
__global__ __launch_bounds__(256, 4) void k_kv(
    const float* __restrict__ enc, u16* __restrict__ KV,
    const u16* __restrict__ w0T, const u16* __restrict__ w1T,
    const u16* __restrict__ w2T, const u16* __restrict__ w3T,
    const float* __restrict__ b0, const float* __restrict__ b1,
    const float* __restrict__ b2, const float* __restrict__ b3)
{
    __shared__ __align__(16) u16 aL[64 * SA];
    const int tid = threadIdx.x, lane = tid & 63, w = tid >> 6;
    const size_t t0 = (size_t)blockIdx.x * 64;
    const int nb = w * 64, ar = lane & 15, g = lane >> 4, kg = g * 8;

    for (int idx = tid; idx < 64 * 32; idx += 256) {
        int r = idx >> 5, c8 = (idx & 31) << 3;
        const float* ep = enc + (t0 + r) * 256 + c8;
        const float4 v0 = *(const float4*)ep;
        const float4 v1 = *(const float4*)(ep + 4);
        u16* p = aL + r * SA + c8;
        p[0] = f2bf(v0.x); p[1] = f2bf(v0.y); p[2] = f2bf(v0.z); p[3] = f2bf(v0.w);
        p[4] = f2bf(v1.x); p[5] = f2bf(v1.y); p[6] = f2bf(v1.z); p[7] = f2bf(v1.w);
    }
    __syncthreads();

    const u16* Ws[4] = {w0T, w1T, w2T, w3T};
    const float* Bs[4] = {b0, b1, b2, b3};
#pragma unroll
    for (int t = 0; t < 4; ++t) {
        f32x4 acc[4][4] = {};
        for (int k0 = 0; k0 < 256; k0 += 32) {
            bf16x8 a[4], bb[4];
#pragma unroll
            for (int mt = 0; mt < 4; ++mt)
                a[mt] = *(const bf16x8*)(aL + (mt * 16 + ar) * SA + k0 + kg);
#pragma unroll
            for (int nt = 0; nt < 4; ++nt)
                bb[nt] = *(const bf16x8*)(Ws[t] + (nb + nt * 16 + ar) * 256 + k0 + kg);
#pragma unroll
            for (int mt = 0; mt < 4; ++mt)
#pragma unroll
                for (int nt = 0; nt < 4; ++nt)
                    acc[mt][nt] = __builtin_amdgcn_mfma_f32_16x16x32_bf16(a[mt], bb[nt], acc[mt][nt], 0, 0, 0);
        }
#pragma unroll
        for (int mt = 0; mt < 4; ++mt)
#pragma unroll
            for (int nt = 0; nt < 4; ++nt) {
                int col = nb + nt * 16 + (lane & 15);
                float bias = Bs[t][col];
#pragma unroll
                for (int r = 0; r < 4; ++r) {
                    int row = mt * 16 + g * 4 + r;
                    KV[(t0 + row) * 1024 + t * 256 + col] = f2bf(acc[mt][nt][r] + bias);
                }
            }
    }
}

// ---------------- fused windowed attention: 4 FAT waves (wave = head, acc[4][4]) ----------------
// grid 4096, block 256. LDS 81.7 KB -> 2 blocks/CU (8 waves/CU), barriers sync 4 waves.
__global__ __launch_bounds__(256, 2) void k_win_attn2(
    const float* src, float* dst, const u16* __restrict__ KV, int kvoff,
    const float* __restrict__ lng, const float* __restrict__ lnb,
    const u16* __restrict__ wqT, const u16* __restrict__ wpT,
    const float* __restrict__ bq, const float* __restrict__ bp,
    const float* __restrict__ rpb, int shift)
{
    // tA: yL [49][264] -> V [49][264]      (25,872 B @ 0)
    // tB: Q/P [4][49][72] -> O [49][264]   (28,224 B @ 25,872)
    // tC: K [49][264]                      (25,872 B @ 54,096)
    __shared__ __align__(16) char smem[81728];
    u16* tA = (u16*)(smem);
    u16* tB = (u16*)(smem + 25872);
    u16* tC = (u16*)(smem + 54096);
    int* t_idx = (int*)(smem + 79968);
    int* label = (int*)(smem + 80164);
    u16* rpbL  = (u16*)(smem + 80360);   // [169][4] bf16 rel-pos bias

    const int tid = threadIdx.x, lane = tid & 63;
    const int s = tid >> 6;                 // wave = head
    const int l15 = lane & 15, g = lane >> 4, kg = g * 8;
    const int nb = s * 64;

    const int wi = blockIdx.x;
    const int b  = wi >> 10;
    const int wl = wi & 1023;
    const int wh = wl >> 5, wwi = wl & 31;

    if (tid < NTOK) {
        int yi = tid / 7, xi = tid - yi * 7;
        int h = wh * 7 + yi + shift; if (h >= 224) h -= 224;
        int ww = wwi * 7 + xi + shift; if (ww >= 224) ww -= 224;
        t_idx[tid] = (b * 224 + h) * 224 + ww;
        int hp = wh * 7 + yi, wp = wwi * 7 + xi;   // rolled-frame coords
        int rh = (hp < 217) ? 0 : ((hp < 221) ? 1 : 2);
        int rw = (wp < 217) ? 0 : ((wp < 221) ? 1 : 2);
        label[tid] = rh * 3 + rw;
    }
    for (int i = tid; i < 676; i += 256) rpbL[i] = f2bf(rpb[i]);
    __syncthreads();

    // ---- p1: LN(src) -> tA ; stage K window -> tC (all 4 waves, back to back) ----
    for (int r = s; r < NTOK; r += 4) {
        const float4 xv = *(const float4*)(src + (size_t)t_idx[r] * 256 + lane * 4);
        float xs[4] = {xv.x, xv.y, xv.z, xv.w};
        float sm = xs[0] + xs[1] + xs[2] + xs[3];
        float s2 = xs[0] * xs[0] + xs[1] * xs[1] + xs[2] * xs[2] + xs[3] * xs[3];
#pragma unroll
        for (int m = 1; m < 64; m <<= 1) { sm += __shfl_xor(sm, m); s2 += __shfl_xor(s2, m); }
        float mean = sm * (1.0f / 256.0f);
        float var = s2 * (1.0f / 256.0f) - mean * mean;
        float rstd = rsqrtf(fmaxf(var, 0.0f) + 1e-12f);
#pragma unroll
        for (int j = 0; j < 4; ++j) {
            int c = lane * 4 + j;
            tA[r * SA + c] = f2bf((xs[j] - mean) * rstd * lng[c] + lnb[c]);
        }
    }
    for (int r = s; r < NTOK; r += 4)
        *(ushort4*)(tC + r * SA + lane * 4) =
            *(const ushort4*)(KV + (size_t)t_idx[r] * 1024 + kvoff + lane * 4);
    __syncthreads();

    // ---- p2: Q = (yL @ wq + bq) * scale -> tB per-head [4][49][72] ----
    {
        f32x4 acc[4][4] = {};
        gemm49f(tA, wqT, nb, lane, acc);
#pragma unroll
        for (int mt = 0; mt < 4; ++mt)
#pragma unroll
            for (int nt = 0; nt < 4; ++nt) {
                int col = nb + nt * 16 + l15;
                float bias = bq[col];
#pragma unroll
                for (int r = 0; r < 4; ++r) {
                    int row = mt * 16 + g * 4 + r;
                    if (row < NTOK)
                        tB[s * (NTOK * SP) + row * SP + nt * 16 + l15] =
                            f2bf((acc[mt][nt][r] + bias) * 0.125f);
                }
            }
    }
    __syncthreads();   // yL reads done -> tA reusable

    // ---- p3: stage V -> tA ; QK^T (K from tC) ; softmax in regs ----
    for (int r = s; r < NTOK; r += 4)
        *(ushort4*)(tA + r * SA + lane * 4) =
            *(const ushort4*)(KV + (size_t)t_idx[r] * 1024 + kvoff + 256 + lane * 4);

    f32x4 sa[4][4] = {};
    {
        const bf16x8 z = zfrag();
        for (int k0 = 0; k0 < 64; k0 += 32) {
            bf16x8 a[4], bb[4];
#pragma unroll
            for (int mt = 0; mt < 4; ++mt) {
                int row = mt * 16 + l15;
                a[mt] = (row < NTOK) ? *(const bf16x8*)(tB + s * (NTOK * SP) + row * SP + k0 + kg) : z;
            }
#pragma unroll
            for (int nt = 0; nt < 4; ++nt) {
                int col = nt * 16 + l15;
                bb[nt] = (col < NTOK) ? *(const bf16x8*)(tC + col * SA + s * 64 + k0 + kg) : z;
            }
#pragma unroll
            for (int mt = 0; mt < 4; ++mt)
#pragma unroll
                for (int nt = 0; nt < 4; ++nt)
                    sa[mt][nt] = __builtin_amdgcn_mfma_f32_16x16x32_bf16(a[mt], bb[nt], sa[mt][nt], 0, 0, 0);
        }
#pragma unroll
        for (int mt = 0; mt < 4; ++mt) {
#pragma unroll
            for (int rr = 0; rr < 4; ++rr) {
                int i = mt * 16 + g * 4 + rr;
                bool iv = (i < NTOK);
                int yi = iv ? (i / 7) : 0, xi = iv ? (i - (i / 7) * 7) : 0;
                int li = iv ? label[i] : 0;
                float v[4], mx = -1e30f;
#pragma unroll
                for (int nt = 0; nt < 4; ++nt) {
                    int j = nt * 16 + l15;
                    float t = -1e30f;
                    if (iv && j < NTOK) {
                        t = sa[mt][nt][rr];
                        int yj = j / 7, xj = j - (j / 7) * 7;
                        t += bf2f(rpbL[((yi - yj + 6) * 13 + (xi - xj + 6)) * 4 + s]);
                        if (shift > 0 && li != label[j]) t -= 100.0f;
                    }
                    v[nt] = t;
                    mx = fmaxf(mx, t);
                }
#pragma unroll
                for (int mk = 1; mk < 16; mk <<= 1) mx = fmaxf(mx, __shfl_xor(mx, mk));
                float sum = 0.f, e[4];
#pragma unroll
                for (int nt = 0; nt < 4; ++nt) {
                    e[nt] = (v[nt] > -1e29f) ? __expf(v[nt] - mx) : 0.0f;
                    sum += e[nt];
                }
#pragma unroll
                for (int mk = 1; mk < 16; mk <<= 1) sum += __shfl_xor(sum, mk);
                float inv = 1.0f / sum;
#pragma unroll
                for (int nt = 0; nt < 4; ++nt) sa[mt][nt][rr] = e[nt] * inv;
            }
        }
    }
    __syncthreads();   // V staged; Q/K reads done

    // ---- p4: store P (wave-private rows) ; PV (V via LDS gather) ----
    f32x4 oa[4][4] = {};
    {
#pragma unroll
        for (int mt = 0; mt < 4; ++mt)
#pragma unroll
            for (int rr = 0; rr < 4; ++rr) {
                int i = mt * 16 + g * 4 + rr;
                if (i < NTOK) {
                    u16* Prow = tB + s * (NTOK * SP) + i * SP;
#pragma unroll
                    for (int nt = 0; nt < 4; ++nt) Prow[nt * 16 + l15] = f2bf(sa[mt][nt][rr]);
                }
            }
        const bf16x8 z = zfrag();
        for (int k0 = 0; k0 < 64; k0 += 32) {
            bf16x8 a[4], bb[4];
#pragma unroll
            for (int mt = 0; mt < 4; ++mt) {
                int row = mt * 16 + l15;
                a[mt] = (row < NTOK) ? *(const bf16x8*)(tB + s * (NTOK * SP) + row * SP + k0 + kg) : z;
            }
#pragma unroll
            for (int nt = 0; nt < 4; ++nt) {
                u16 tmp[8];
#pragma unroll
                for (int i = 0; i < 8; ++i) {
                    int tok = k0 + kg + i;
                    tmp[i] = (tok < NTOK) ? tA[tok * SA + s * 64 + nt * 16 + l15] : (u16)0;
                }
                bb[nt] = *(bf16x8*)tmp;
            }
#pragma unroll
            for (int mt = 0; mt < 4; ++mt)
#pragma unroll
                for (int nt = 0; nt < 4; ++nt)
                    oa[mt][nt] = __builtin_amdgcn_mfma_f32_16x16x32_bf16(a[mt], bb[nt], oa[mt][nt], 0, 0, 0);
        }
    }
    __syncthreads();   // PV reads done -> tB reusable as O [49][264]
#pragma unroll
    for (int mt = 0; mt < 4; ++mt)
#pragma unroll
        for (int nt = 0; nt < 4; ++nt) {
            int col = s * 64 + nt * 16 + l15;
#pragma unroll
            for (int r = 0; r < 4; ++r) {
                int row = mt * 16 + g * 4 + r;
                if (row < NTOK) tB[row * SA + col] = f2bf(oa[mt][nt][r]);
            }
        }
    __syncthreads();   // O complete

    // ---- p5: dst = src + O @ Wp + bp ----
    {
        f32x4 acc[4][4] = {};
        gemm49f(tB, wpT, nb, lane, acc);
#pragma unroll
        for (int mt = 0; mt < 4; ++mt)
#pragma unroll
            for (int nt = 0; nt < 4; ++nt) {
                int col = nb + nt * 16 + l15;
                float bias = bp[col];
#pragma unroll
                for (int r = 0; r < 4; ++r) {
                    int row = mt * 16 + g * 4 + r;
                    if (row < NTOK) {
                        size_t off = (size_t)t_idx[row] * 256 + col;
                        dst[off] = src[off] + acc[mt][nt][r] + bias;
                    }
                }
            }
    }
}

// ---------------- fused MLP (r12 best: 8x128 chunks, double-buffered hL) ----------------
#define SM 264
__global__ __launch_bounds__(256) void k_mlp(
    float* R,
    const float* __restrict__ lng, const float* __restrict__ lnb,
    const u16* __restrict__ fc1T, const float* __restrict__ fc1b,
    const u16* __restrict__ fc2T, const float* __restrict__ fc2b)
{
    __shared__ __align__(16) u16 yL[64 * SM];
    __shared__ __align__(16) u16 hb[2][64 * SH];
    const int tid = threadIdx.x, lane = tid & 63, wave = tid >> 6;
    const size_t t0 = (size_t)blockIdx.x * 64;
    const int nb = wave * 64;
    const int cb = wave * 32;
    const int ar = lane & 15, g = lane >> 4, kg = g * 8;

    for (int r = wave; r < 64; r += 4) {
        const float4 xv = *(const float4*)(R + (t0 + r) * 256 + lane * 4);
        float xs[4] = {xv.x, xv.y, xv.z, xv.w};
        float s = xs[0] + xs[1] + xs[2] + xs[3];
        float s2 = xs[0] * xs[0] + xs[1] * xs[1] + xs[2] * xs[2] + xs[3] * xs[3];
#pragma unroll
        for (int m = 1; m < 64; m <<= 1) { s += __shfl_xor(s, m); s2 += __shfl_xor(s2, m); }
        float mean = s * (1.0f / 256.0f);
        float var = s2 * (1.0f / 256.0f) - mean * mean;
        float rstd = rsqrtf(fmaxf(var, 0.0f) + 1e-12f);
#pragma unroll
        for (int j = 0; j < 4; ++j) {
            int c = lane * 4 + j;
            yL[r * SM + c] = f2bf((xs[j] - mean) * rstd * lng[c] + lnb[c]);
        }
    }
    __syncthreads();

    auto G1 = [&](int ch) {
        f32x4 acc1[4][2] = {};
        for (int k0 = 0; k0 < 256; k0 += 32) {
            bf16x8 a[4], bb[2];
#pragma unroll
            for (int mt = 0; mt < 4; ++mt)
                a[mt] = *(const bf16x8*)(yL + (mt * 16 + ar) * SM + k0 + kg);
#pragma unroll
            for (int nt = 0; nt < 2; ++nt) {
                int hidx = ch * 128 + cb + nt * 16 + ar;
                bb[nt] = *(const bf16x8*)(fc1T + (size_t)hidx * 256 + k0 + kg);
            }
#pragma unroll
            for (int mt = 0; mt < 4; ++mt)
#pragma unroll
                for (int nt = 0; nt < 2; ++nt)
                    acc1[mt][nt] = __builtin_amdgcn_mfma_f32_16x16x32_bf16(a[mt], bb[nt], acc1[mt][nt], 0, 0, 0);
        }
        u16* hp = hb[ch & 1];
#pragma unroll
        for (int mt = 0; mt < 4; ++mt)
#pragma unroll
            for (int nt = 0; nt < 2; ++nt) {
                int lcol = cb + nt * 16 + ar;
                float bias = fc1b[ch * 128 + lcol];
#pragma unroll
                for (int r = 0; r < 4; ++r) {
                    int row = mt * 16 + g * 4 + r;
                    hp[row * SH + lcol] = f2bf(gelu_f(acc1[mt][nt][r] + bias));
                }
            }
    };

    f32x4 acc2[4][4] = {};
    G1(0);
    __syncthreads();
    for (int c = 0; c < 8; ++c) {
        if (c < 7) G1(c + 1);
        const u16* hp = hb[c & 1];
        for (int k0 = 0; k0 < 128; k0 += 32) {
            bf16x8 a[4], bb[4];
#pragma unroll
            for (int mt = 0; mt < 4; ++mt)
                a[mt] = *(const bf16x8*)(hp + (mt * 16 + ar) * SH + k0 + kg);
#pragma unroll
            for (int nt = 0; nt < 4; ++nt) {
                int col = nb + nt * 16 + ar;
                bb[nt] = *(const bf16x8*)(fc2T + (size_t)col * 1024 + c * 128 + k0 + kg);
            }
#pragma unroll
            for (int mt = 0; mt < 4; ++mt)
#pragma unroll
                for (int nt = 0; nt < 4; ++nt)
                    acc2[mt][nt] = __builtin_amdgcn_mfma_f32_16x16x32_bf16(a[mt], bb[nt], acc2[mt][nt], 0, 0, 0);
        }
        if (c < 7) __syncthreads();
    }
#pragma unroll
    for (int mt = 0; mt < 4; ++mt)
#pragma unroll
        for (int nt = 0; nt < 4; ++nt) {
            int col = nb + nt * 16 + (lane & 15);
            float bias = fc2b[col];
#pragma unroll
            for (int r = 0; r < 4; ++r) {
                int row = mt * 16 + g * 4 + r;
                size_t off = (t0 + row) * 256 + col;
                R[off] = acc2[mt][nt][r] + bias + R[off];
            }
        }
}

extern "C" void kernel_launch(void* const* d_in, const int* in_sizes, int n_in,
                              void* d_out, int out_size, void* d_ws, size_t ws_size,
                              hipStream_t stream) {
    (void)in_sizes; (void)n_in; (void)out_size; (void)ws_size;
    // ws layout: [0, 2MB): transposed bf16 weights; [2MB, +411MB): KV [T_TOK][1024] bf16.
    u16* WTbase = (u16*)d_ws;
    u16* wT[8];
    for (int i = 0; i < 8; ++i) wT[i] = WTbase + (size_t)i * 65536;
    u16* fc1T = WTbase + (size_t)8 * 65536;      // [1024][256]
    u16* fc2T = fc1T + 262144;                   // [256][1024]
    u16* KV = WTbase + 1048576;                  // [T_TOK][1024] bf16: k1|v1|k2|v2

    TPack tp;
    const int wsrc[8] = {10, 11, 12, 13, 19, 20, 21, 22};
    for (int i = 0; i < 8; ++i) {
        tp.in[i] = (const float*)d_in[wsrc[i]]; tp.out[i] = wT[i];
        tp.K[i] = 256; tp.N[i] = 256;
    }
    tp.in[8] = (const float*)d_in[28]; tp.out[8] = fc1T; tp.K[8] = 256;  tp.N[8] = 1024;
    tp.in[9] = (const float*)d_in[30]; tp.out[9] = fc2T; tp.K[9] = 1024; tp.N[9] = 256;
    k_transpose_all<<<dim3(1024, 10), 256, 0, stream>>>(tp);

    float* R = (float*)d_out;   // fp32 residual stream in d_out

    k_kv<<<T_TOK / 64, 256, 0, stream>>>((const float*)d_in[1], KV,
        wT[1], wT[2], wT[5], wT[6],
        (const float*)d_in[15], (const float*)d_in[16],
        (const float*)d_in[24], (const float*)d_in[25]);
    // block 1 (shift=0): R = x + attn1(LN1(x)@wq1, K1, V1)
    k_win_attn2<<<4096, 256, 0, stream>>>((const float*)d_in[0], R, KV, 0,
        (const float*)d_in[4], (const float*)d_in[5], wT[0], wT[3],
        (const float*)d_in[14], (const float*)d_in[17], (const float*)d_in[18], 0);
    // block 2 (shift=3, + shift mask): R += attn2(LN2(R)@wq2, K2, V2)
    k_win_attn2<<<4096, 256, 0, stream>>>(R, R, KV, 512,
        (const float*)d_in[6], (const float*)d_in[7], wT[4], wT[7],
        (const float*)d_in[23], (const float*)d_in[26], (const float*)d_in[27], 3);
    // MLP + final residual, in place on R
    k_mlp<<<T_TOK / 64, 256, 0, stream>>>(R,
        (const float*)d_in[8], (const float*)d_in[9],
        fc1T, (const float*)d_in[29], fc2T, (const float*)d_in[31]);
}

// Round 14
// 1942.247 us; speedup vs baseline: 1.0198x; 1.0198x over previous
//
#include <hip/hip_runtime.h>

typedef unsigned short u16;
typedef __bf16 bf16x8 __attribute__((ext_vector_type(8)));
typedef float f32x4 __attribute__((ext_vector_type(4)));

#define T_TOK 200704   // 4*224*224
#define NTOK 49
#define SA 264         // stride (u16) for [49][256]/[64][256] LDS tiles
#define SP 72          // per-head Q/P row stride (144 B)
#define SH 136         // mlp hidden-chunk LDS stride (272 B rows)

__device__ __forceinline__ u16 f2bf(float f) {
    union { float f; unsigned u; } v; v.f = f;
    return (u16)((v.u + 0x7FFFu + ((v.u >> 16) & 1u)) >> 16);
}
__device__ __forceinline__ float bf2f(u16 b) {
    union { float f; unsigned u; } v; v.u = ((unsigned)b) << 16; return v.f;
}
__device__ __forceinline__ bf16x8 zfrag() {
    bf16x8 z;
#pragma unroll
    for (int i = 0; i < 8; ++i) z[i] = (__bf16)0.0f;
    return z;
}
// fast gelu (tanh form; validated r10, absmax unchanged)
__device__ __forceinline__ float gelu_f(float x) {
    float z = 0.7978845608f * (x + 0.044715f * x * x * x);
    float az = fabsf(z);
    float e = __expf(-2.0f * az);
    float t = (1.0f - e) / (1.0f + e);
    t = (z < 0.0f) ? -t : t;
    return 0.5f * x * (1.0f + t);
}

// ---------------- merged transpose: 10 matrices in one launch ----------------
struct TPack {
    const float* in[10];
    u16* out[10];
    int K[10], N[10];
};
__global__ void k_transpose_all(TPack p) {
    const int m = blockIdx.y;
    const int K = p.K[m], N = p.N[m];
    int idx = blockIdx.x * blockDim.x + threadIdx.x;
    if (idx >= K * N) return;
    int k = idx / N, n = idx - k * N;
    p.out[m][n * K + k] = f2bf(p.in[m][idx]);
}

// Half-height GEMM helper (A stride SA in LDS, WT bf16 global [n][256]).
__device__ __forceinline__ void gemm49h(const u16* A, const u16* WT,
                                        int nb, int mtb, int lane, f32x4 acc[2][4]) {
    const int ar = lane & 15;
    const int kg = (lane >> 4) * 8;
    const bf16x8 z = zfrag();
    for (int k0 = 0; k0 < 256; k0 += 32) {
        bf16x8 a[2], bb[4];
#pragma unroll
        for (int m = 0; m < 2; ++m) {
            int row = (mtb + m) * 16 + ar;
            a[m] = (row < NTOK) ? *(const bf16x8*)(A + row * SA + k0 + kg) : z;
        }
#pragma unroll
        for (int nt = 0; nt < 4; ++nt) {
            int col = nb + nt * 16 + ar;
            bb[nt] = *(const bf16x8*)(WT + col * 256 + k0 + kg);
        }
#pragma unroll
        for (int m = 0; m < 2; ++m)
#pragma unroll
            for (int nt = 0; nt < 4; ++nt)
                acc[m][nt] = __builtin_amdgcn_mfma_f32_16x16x32_bf16(a[m], bb[nt], acc[m][nt], 0, 0, 0);
    }
}

// ---------------- dense KV projection: stage enc ONCE, 4 outputs ----------------
__global__ __launch_bounds__(256, 4) void k_kv(
    const float* __restrict__ enc, u16* __restrict__ KV,
    const u16* __restrict__ w0T, const u16* __restrict__ w1T,
    const u16* __restrict__ w2T, const u16* __restrict__ w3T,
    const float* __restrict__ b0, const float* __restrict__ b1,
    const float* __restrict__ b2, const float* __restrict__ b3)
{
    __shared__ __align__(16) u16 aL[64 * SA];
    const int tid = threadIdx.x, lane = tid & 63, w = tid >> 6;
    const size_t t0 = (size_t)blockIdx.x * 64;
    const int nb = w * 64, ar = lane & 15, g = lane >> 4, kg = g * 8;

    for (int idx = tid; idx < 64 * 32; idx += 256) {
        int r = idx >> 5, c8 = (idx & 31) << 3;
        const float* ep = enc + (t0 + r) * 256 + c8;
        const float4 v0 = *(const float4*)ep;
        const float4 v1 = *(const float4*)(ep + 4);
        u16* p = aL + r * SA + c8;
        p[0] = f2bf(v0.x); p[1] = f2bf(v0.y); p[2] = f2bf(v0.z); p[3] = f2bf(v0.w);
        p[4] = f2bf(v1.x); p[5] = f2bf(v1.y); p[6] = f2bf(v1.z); p[7] = f2bf(v1.w);
    }
    __syncthreads();

    const u16* Ws[4] = {w0T, w1T, w2T, w3T};
    const float* Bs[4] = {b0, b1, b2, b3};
#pragma unroll
    for (int t = 0; t < 4; ++t) {
        f32x4 acc[4][4] = {};
        for (int k0 = 0; k0 < 256; k0 += 32) {
            bf16x8 a[4], bb[4];
#pragma unroll
            for (int mt = 0; mt < 4; ++mt)
                a[mt] = *(const bf16x8*)(aL + (mt * 16 + ar) * SA + k0 + kg);
#pragma unroll
            for (int nt = 0; nt < 4; ++nt)
                bb[nt] = *(const bf16x8*)(Ws[t] + (nb + nt * 16 + ar) * 256 + k0 + kg);
#pragma unroll
            for (int mt = 0; mt < 4; ++mt)
#pragma unroll
                for (int nt = 0; nt < 4; ++nt)
                    acc[mt][nt] = __builtin_amdgcn_mfma_f32_16x16x32_bf16(a[mt], bb[nt], acc[mt][nt], 0, 0, 0);
        }
#pragma unroll
        for (int mt = 0; mt < 4; ++mt)
#pragma unroll
            for (int nt = 0; nt < 4; ++nt) {
                int col = nb + nt * 16 + (lane & 15);
                float bias = Bs[t][col];
#pragma unroll
                for (int r = 0; r < 4; ++r) {
                    int row = mt * 16 + g * 4 + r;
                    KV[(t0 + row) * 1024 + t * 256 + col] = f2bf(acc[mt][nt][r] + bias);
                }
            }
    }
}

// ---------------- fused windowed attention (KV precomputed, K+V in LDS) ----------------
// grid 4096, block 512 (8 waves: head s=w&3, row-half hf=w>>2). 81.7 KB -> 2 blocks/CU.
__global__ __launch_bounds__(512, 4) void k_win_attn2(
    const float* src, float* dst, const u16* __restrict__ KV, int kvoff,
    const float* __restrict__ lng, const float* __restrict__ lnb,
    const u16* __restrict__ wqT, const u16* __restrict__ wpT,
    const float* __restrict__ bq, const float* __restrict__ bp,
    const float* __restrict__ rpb, int shift)
{
    // tA: yL [49][264] -> V [49][264]      (25,872 B @ 0)
    // tB: Q/P [4][49][72] -> O [49][264]   (28,224 B @ 25,872)
    // tC: K [49][264]                      (25,872 B @ 54,096)
    __shared__ __align__(16) char smem[81728];
    u16* tA = (u16*)(smem);
    u16* tB = (u16*)(smem + 25872);
    u16* tC = (u16*)(smem + 54096);
    int* t_idx = (int*)(smem + 79968);
    int* label = (int*)(smem + 80164);
    u16* rpbL  = (u16*)(smem + 80360);   // [169][4] bf16 rel-pos bias

    const int tid = threadIdx.x, lane = tid & 63;
    const int w = tid >> 6;
    const int s  = w & 3;        // head / col strip
    const int hf = w >> 2;       // row half
    const int mtb = hf * 2;
    const int l15 = lane & 15, g = lane >> 4, kg = g * 8;
    const int nb = s * 64;

    const int wi = blockIdx.x;
    const int b  = wi >> 10;
    const int wl = wi & 1023;
    const int wh = wl >> 5, wwi = wl & 31;

    if (tid < NTOK) {
        int yi = tid / 7, xi = tid - yi * 7;
        int h = wh * 7 + yi + shift; if (h >= 224) h -= 224;
        int ww = wwi * 7 + xi + shift; if (ww >= 224) ww -= 224;
        t_idx[tid] = (b * 224 + h) * 224 + ww;
        int hp = wh * 7 + yi, wp = wwi * 7 + xi;   // rolled-frame coords
        int rh = (hp < 217) ? 0 : ((hp < 221) ? 1 : 2);
        int rw = (wp < 217) ? 0 : ((wp < 221) ? 1 : 2);
        label[tid] = rh * 3 + rw;
    }
    for (int i = tid; i < 676; i += 512) rpbL[i] = f2bf(rpb[i]);
    __syncthreads();

    // ---- p1: waves 0-3: LN(src) -> tA ; waves 4-7: stage K window -> tC ----
    if (hf == 0) {
        for (int r = s; r < NTOK; r += 4) {
            const float4 xv = *(const float4*)(src + (size_t)t_idx[r] * 256 + lane * 4);
            float xs[4] = {xv.x, xv.y, xv.z, xv.w};
            float sm = xs[0] + xs[1] + xs[2] + xs[3];
            float s2 = xs[0] * xs[0] + xs[1] * xs[1] + xs[2] * xs[2] + xs[3] * xs[3];
#pragma unroll
            for (int m = 1; m < 64; m <<= 1) { sm += __shfl_xor(sm, m); s2 += __shfl_xor(s2, m); }
            float mean = sm * (1.0f / 256.0f);
            float var = s2 * (1.0f / 256.0f) - mean * mean;
            float rstd = rsqrtf(fmaxf(var, 0.0f) + 1e-12f);
#pragma unroll
            for (int j = 0; j < 4; ++j) {
                int c = lane * 4 + j;
                tA[r * SA + c] = f2bf((xs[j] - mean) * rstd * lng[c] + lnb[c]);
            }
        }
    } else {
        for (int r = s; r < NTOK; r += 4)
            *(ushort4*)(tC + r * SA + lane * 4) =
                *(const ushort4*)(KV + (size_t)t_idx[r] * 1024 + kvoff + lane * 4);
    }
    __syncthreads();

    // ---- p2: Q = (yL @ wq + bq) * scale -> tB per-head [4][49][72] ----
    {
        f32x4 acc[2][4] = {};
        gemm49h(tA, wqT, nb, mtb, lane, acc);
#pragma unroll
        for (int m = 0; m < 2; ++m)
#pragma unroll
            for (int nt = 0; nt < 4; ++nt) {
                int col = nb + nt * 16 + l15;
                float bias = bq[col];
#pragma unroll
                for (int r = 0; r < 4; ++r) {
                    int row = (mtb + m) * 16 + g * 4 + r;
                    if (row < NTOK)
                        tB[s * (NTOK * SP) + row * SP + nt * 16 + l15] =
                            f2bf((acc[m][nt][r] + bias) * 0.125f);
                }
            }
    }
    __syncthreads();   // yL reads done -> tA reusable

    // ---- p3: stage V -> tA ; QK^T (K from tC LDS) ; softmax in regs ----
    for (int r = w; r < NTOK; r += 8)
        *(ushort4*)(tA + r * SA + lane * 4) =
            *(const ushort4*)(KV + (size_t)t_idx[r] * 1024 + kvoff + 256 + lane * 4);

    f32x4 sa[2][4] = {};
    {
        const bf16x8 z = zfrag();
        for (int k0 = 0; k0 < 64; k0 += 32) {
            bf16x8 a[2], bb[4];
#pragma unroll
            for (int m = 0; m < 2; ++m) {
                int row = (mtb + m) * 16 + l15;
                a[m] = (row < NTOK) ? *(const bf16x8*)(tB + s * (NTOK * SP) + row * SP + k0 + kg) : z;
            }
#pragma unroll
            for (int nt = 0; nt < 4; ++nt) {
                int col = nt * 16 + l15;
                bb[nt] = (col < NTOK) ? *(const bf16x8*)(tC + col * SA + s * 64 + k0 + kg) : z;
            }
#pragma unroll
            for (int m = 0; m < 2; ++m)
#pragma unroll
                for (int nt = 0; nt < 4; ++nt)
                    sa[m][nt] = __builtin_amdgcn_mfma_f32_16x16x32_bf16(a[m], bb[nt], sa[m][nt], 0, 0, 0);
        }
#pragma unroll
        for (int m = 0; m < 2; ++m) {
#pragma unroll
            for (int rr = 0; rr < 4; ++rr) {
                int i = (mtb + m) * 16 + g * 4 + rr;
                bool iv = (i < NTOK);
                int yi = iv ? (i / 7) : 0, xi = iv ? (i - (i / 7) * 7) : 0;
                int li = iv ? label[i] : 0;
                float v[4], mx = -1e30f;
#pragma unroll
                for (int nt = 0; nt < 4; ++nt) {
                    int j = nt * 16 + l15;
                    float t = -1e30f;
                    if (iv && j < NTOK) {
                        t = sa[m][nt][rr];
                        int yj = j / 7, xj = j - (j / 7) * 7;
                        t += bf2f(rpbL[((yi - yj + 6) * 13 + (xi - xj + 6)) * 4 + s]);
                        if (shift > 0 && li != label[j]) t -= 100.0f;
                    }
                    v[nt] = t;
                    mx = fmaxf(mx, t);
                }
#pragma unroll
                for (int mk = 1; mk < 16; mk <<= 1) mx = fmaxf(mx, __shfl_xor(mx, mk));
                float sum = 0.f, e[4];
#pragma unroll
                for (int nt = 0; nt < 4; ++nt) {
                    e[nt] = (v[nt] > -1e29f) ? __expf(v[nt] - mx) : 0.0f;
                    sum += e[nt];
                }
#pragma unroll
                for (int mk = 1; mk < 16; mk <<= 1) sum += __shfl_xor(sum, mk);
                float inv = 1.0f / sum;
#pragma unroll
                for (int nt = 0; nt < 4; ++nt) sa[m][nt][rr] = e[nt] * inv;
            }
        }
    }
    __syncthreads();   // V staged (cross-wave); Q/K reads done

    // ---- p4: store P (wave-private rows) ; PV (V via LDS gather) ----
    f32x4 oa[2][4] = {};
    {
#pragma unroll
        for (int m = 0; m < 2; ++m)
#pragma unroll
            for (int rr = 0; rr < 4; ++rr) {
                int i = (mtb + m) * 16 + g * 4 + rr;
                if (i < NTOK) {
                    u16* Prow = tB + s * (NTOK * SP) + i * SP;
#pragma unroll
                    for (int nt = 0; nt < 4; ++nt) Prow[nt * 16 + l15] = f2bf(sa[m][nt][rr]);
                }
            }
        const bf16x8 z = zfrag();
        for (int k0 = 0; k0 < 64; k0 += 32) {
            bf16x8 a[2], bb[4];
#pragma unroll
            for (int m = 0; m < 2; ++m) {
                int row = (mtb + m) * 16 + l15;
                a[m] = (row < NTOK) ? *(const bf16x8*)(tB + s * (NTOK * SP) + row * SP + k0 + kg) : z;
            }
#pragma unroll
            for (int nt = 0; nt < 4; ++nt) {
                u16 tmp[8];
#pragma unroll
                for (int i = 0; i < 8; ++i) {
                    int tok = k0 + kg + i;
                    tmp[i] = (tok < NTOK) ? tA[tok * SA + s * 64 + nt * 16 + l15] : (u16)0;
                }
                bb[nt] = *(bf16x8*)tmp;
            }
#pragma unroll
            for (int m = 0; m < 2; ++m)
#pragma unroll
                for (int nt = 0; nt < 4; ++nt)
                    oa[m][nt] = __builtin_amdgcn_mfma_f32_16x16x32_bf16(a[m], bb[nt], oa[m][nt], 0, 0, 0);
        }
    }
    __syncthreads();   // all PV reads done -> tB reusable as O [49][264]
#pragma unroll
    for (int m = 0; m < 2; ++m)
#pragma unroll
        for (int nt = 0; nt < 4; ++nt) {
            int col = s * 64 + nt * 16 + l15;
#pragma unroll
            for (int r = 0; r < 4; ++r) {
                int row = (mtb + m) * 16 + g * 4 + r;
                if (row < NTOK) tB[row * SA + col] = f2bf(oa[m][nt][r]);
            }
        }
    __syncthreads();   // O complete

    // ---- p5: dst = src + O @ Wp + bp ----
    {
        f32x4 acc[2][4] = {};
        gemm49h(tB, wpT, nb, mtb, lane, acc);
#pragma unroll
        for (int m = 0; m < 2; ++m)
#pragma unroll
            for (int nt = 0; nt < 4; ++nt) {
                int col = nb + nt * 16 + l15;
                float bias = bp[col];
#pragma unroll
                for (int r = 0; r < 4; ++r) {
                    int row = (mtb + m) * 16 + g * 4 + r;
                    if (row < NTOK) {
                        size_t off = (size_t)t_idx[row] * 256 + col;
                        dst[off] = src[off] + acc[m][nt][r] + bias;
                    }
                }
            }
    }
}

// ---------------- fused MLP (in place): 8x128-col chunks, double-buffered hL ----------------
#define SM 264
__global__ __launch_bounds__(256) void k_mlp(
    float* R,
    const float* __restrict__ lng, const float* __restrict__ lnb,
    const u16* __restrict__ fc1T, const float* __restrict__ fc1b,
    const u16* __restrict__ fc2T, const float* __restrict__ fc2b)
{
    __shared__ __align__(16) u16 yL[64 * SM];
    __shared__ __align__(16) u16 hb[2][64 * SH];
    const int tid = threadIdx.x, lane = tid & 63, wave = tid >> 6;
    const size_t t0 = (size_t)blockIdx.x * 64;
    const int nb = wave * 64;          // GEMM2 out-col strip
    const int cb = wave * 32;          // GEMM1 in-chunk col substrip
    const int ar = lane & 15, g = lane >> 4, kg = g * 8;

    for (int r = wave; r < 64; r += 4) {
        const float4 xv = *(const float4*)(R + (t0 + r) * 256 + lane * 4);
        float xs[4] = {xv.x, xv.y, xv.z, xv.w};
        float s = xs[0] + xs[1] + xs[2] + xs[3];
        float s2 = xs[0] * xs[0] + xs[1] * xs[1] + xs[2] * xs[2] + xs[3] * xs[3];
#pragma unroll
        for (int m = 1; m < 64; m <<= 1) { s += __shfl_xor(s, m); s2 += __shfl_xor(s2, m); }
        float mean = s * (1.0f / 256.0f);
        float var = s2 * (1.0f / 256.0f) - mean * mean;
        float rstd = rsqrtf(fmaxf(var, 0.0f) + 1e-12f);
#pragma unroll
        for (int j = 0; j < 4; ++j) {
            int c = lane * 4 + j;
            yL[r * SM + c] = f2bf((xs[j] - mean) * rstd * lng[c] + lnb[c]);
        }
    }
    __syncthreads();

    auto G1 = [&](int ch) {
        f32x4 acc1[4][2] = {};
        for (int k0 = 0; k0 < 256; k0 += 32) {
            bf16x8 a[4], bb[2];
#pragma unroll
            for (int mt = 0; mt < 4; ++mt)
                a[mt] = *(const bf16x8*)(yL + (mt * 16 + ar) * SM + k0 + kg);
#pragma unroll
            for (int nt = 0; nt < 2; ++nt) {
                int hidx = ch * 128 + cb + nt * 16 + ar;
                bb[nt] = *(const bf16x8*)(fc1T + (size_t)hidx * 256 + k0 + kg);
            }
#pragma unroll
            for (int mt = 0; mt < 4; ++mt)
#pragma unroll
                for (int nt = 0; nt < 2; ++nt)
                    acc1[mt][nt] = __builtin_amdgcn_mfma_f32_16x16x32_bf16(a[mt], bb[nt], acc1[mt][nt], 0, 0, 0);
        }
        u16* hp = hb[ch & 1];
#pragma unroll
        for (int mt = 0; mt < 4; ++mt)
#pragma unroll
            for (int nt = 0; nt < 2; ++nt) {
                int lcol = cb + nt * 16 + ar;
                float bias = fc1b[ch * 128 + lcol];
#pragma unroll
                for (int r = 0; r < 4; ++r) {
                    int row = mt * 16 + g * 4 + r;
                    hp[row * SH + lcol] = f2bf(gelu_f(acc1[mt][nt][r] + bias));
                }
            }
    };

    f32x4 acc2[4][4] = {};
    G1(0);
    __syncthreads();
    for (int c = 0; c < 8; ++c) {
        if (c < 7) G1(c + 1);   // fills hb[(c+1)&1]; independent of GEMM2(c)
        const u16* hp = hb[c & 1];
        for (int k0 = 0; k0 < 128; k0 += 32) {
            bf16x8 a[4], bb[4];
#pragma unroll
            for (int mt = 0; mt < 4; ++mt)
                a[mt] = *(const bf16x8*)(hp + (mt * 16 + ar) * SH + k0 + kg);
#pragma unroll
            for (int nt = 0; nt < 4; ++nt) {
                int col = nb + nt * 16 + ar;
                bb[nt] = *(const bf16x8*)(fc2T + (size_t)col * 1024 + c * 128 + k0 + kg);
            }
#pragma unroll
            for (int mt = 0; mt < 4; ++mt)
#pragma unroll
                for (int nt = 0; nt < 4; ++nt)
                    acc2[mt][nt] = __builtin_amdgcn_mfma_f32_16x16x32_bf16(a[mt], bb[nt], acc2[mt][nt], 0, 0, 0);
        }
        if (c < 7) __syncthreads();
    }
#pragma unroll
    for (int mt = 0; mt < 4; ++mt)
#pragma unroll
        for (int nt = 0; nt < 4; ++nt) {
            int col = nb + nt * 16 + (lane & 15);
            float bias = fc2b[col];
#pragma unroll
            for (int r = 0; r < 4; ++r) {
                int row = mt * 16 + g * 4 + r;
                size_t off = (t0 + row) * 256 + col;
                R[off] = acc2[mt][nt][r] + bias + R[off];
            }
        }
}

extern "C" void kernel_launch(void* const* d_in, const int* in_sizes, int n_in,
                              void* d_out, int out_size, void* d_ws, size_t ws_size,
                              hipStream_t stream) {
    (void)in_sizes; (void)n_in; (void)out_size; (void)ws_size;
    // ws layout: [0, 2MB): transposed bf16 weights; [2MB, +411MB): KV [T_TOK][1024] bf16.
    u16* WTbase = (u16*)d_ws;
    u16* wT[8];
    for (int i = 0; i < 8; ++i) wT[i] = WTbase + (size_t)i * 65536;
    u16* fc1T = WTbase + (size_t)8 * 65536;      // [1024][256]
    u16* fc2T = fc1T + 262144;                   // [256][1024]
    u16* KV = WTbase + 1048576;                  // [T_TOK][1024] bf16: k1|v1|k2|v2

    TPack tp;
    const int wsrc[8] = {10, 11, 12, 13, 19, 20, 21, 22};
    for (int i = 0; i < 8; ++i) {
        tp.in[i] = (const float*)d_in[wsrc[i]]; tp.out[i] = wT[i];
        tp.K[i] = 256; tp.N[i] = 256;
    }
    tp.in[8] = (const float*)d_in[28]; tp.out[8] = fc1T; tp.K[8] = 256;  tp.N[8] = 1024;
    tp.in[9] = (const float*)d_in[30]; tp.out[9] = fc2T; tp.K[9] = 1024; tp.N[9] = 256;
    k_transpose_all<<<dim3(1024, 10), 256, 0, stream>>>(tp);

    float* R = (float*)d_out;   // fp32 residual stream in d_out

    k_kv<<<T_TOK / 64, 256, 0, stream>>>((const float*)d_in[1], KV,
        wT[1], wT[2], wT[5], wT[6],
        (const float*)d_in[15], (const float*)d_in[16],
        (const float*)d_in[24], (const float*)d_in[25]);
    // block 1 (shift=0): R = x + attn1(LN1(x)@wq1, K1, V1)
    k_win_attn2<<<4096, 512, 0, stream>>>((const float*)d_in[0], R, KV, 0,
        (const float*)d_in[4], (const float*)d_in[5], wT[0], wT[3],
        (const float*)d_in[14], (const float*)d_in[17], (const float*)d_in[18], 0);
    // block 2 (shift=3, + shift mask): R += attn2(LN2(R)@wq2, K2, V2)
    k_win_attn2<<<4096, 512, 0, stream>>>(R, R, KV, 512,
        (const float*)d_in[6], (const float*)d_in[7], wT[4], wT[7],
        (const float*)d_in[23], (const float*)d_in[26], (const float*)d_in[27], 3);
    // MLP + final residual, in place on R
    k_mlp<<<T_TOK / 64, 256, 0, stream>>>(R,
        (const float*)d_in[8], (const float*)d_in[9],
        fc1T, (const float*)d_in[29], fc2T, (const float*)d_in[31]);
}